// Round 1
// baseline (101.138 us; speedup 1.0000x reference)
//
#include <hip/hip_runtime.h>

// ---- order-preserving float<->uint encoding for atomicMax on floats ----
__device__ __forceinline__ unsigned enc_f32(float f) {
    unsigned b = __float_as_uint(f);
    return (b & 0x80000000u) ? ~b : (b | 0x80000000u);
}
__device__ __forceinline__ float dec_f32(unsigned u) {
    unsigned b = (u & 0x80000000u) ? (u & 0x7FFFFFFFu) : ~u;
    return __uint_as_float(b);
}

// ---- pass 1: global max of a table (n fp32 elements) -> encoded atomicMax ----
__global__ void table_max_kernel(const float* __restrict__ t, int n,
                                 unsigned* __restrict__ slot) {
    float m = -INFINITY;
    int stride = gridDim.x * blockDim.x;
    for (int i = blockIdx.x * blockDim.x + threadIdx.x; i < n; i += stride)
        m = fmaxf(m, t[i]);
    // wave64 butterfly reduce
    #pragma unroll
    for (int off = 32; off > 0; off >>= 1)
        m = fmaxf(m, __shfl_down(m, off, 64));
    __shared__ float sm[4];                  // 256 threads = 4 waves
    int lane = threadIdx.x & 63, wid = threadIdx.x >> 6;
    if (lane == 0) sm[wid] = m;
    __syncthreads();
    if (threadIdx.x == 0) {
        float mm = fmaxf(fmaxf(sm[0], sm[1]), fmaxf(sm[2], sm[3]));
        atomicMax(slot, enc_f32(mm));
    }
}

// ---- pass 2: fused gather + affine + pair-sum ----
// out flat index n: row = n>>7, k = n&127.
//   k <  64: table_x row pos[row*2+0], pair (2k, 2k+1)
//   k >= 64: table_y row pos[row*2+1], pair (2(k-64), 2(k-64)+1)
__global__ void lookup_kernel(const int*   __restrict__ pos,
                              const float* __restrict__ fixedt,
                              const float* __restrict__ tx,
                              const float* __restrict__ ty,
                              const unsigned* __restrict__ ws,
                              float* __restrict__ out, int total) {
    const float sx = 0.1f / dec_f32(ws[0]);
    const float sy = 0.1f / dec_f32(ws[1]);
    const int stride = gridDim.x * blockDim.x;   // multiple of 128 -> k pattern stable per lane
    for (int n = blockIdx.x * blockDim.x + threadIdx.x; n < total; n += stride) {
        const int k   = n & 127;
        const int row = n >> 7;
        const bool isx = (k < 64);
        const int  j   = isx ? k : (k - 64);
        int p = pos[row * 2 + (isx ? 0 : 1)];    // wave-uniform broadcast load
        if (p < 0) p = 1;
        const float* tab = isx ? tx : ty;
        const float  s   = isx ? sx : sy;
        const float2 tv = *reinterpret_cast<const float2*>(tab    + p * 128 + 2 * j);
        const float2 fv = *reinterpret_cast<const float2*>(fixedt + p * 128 + 2 * j);
        out[n] = s * (tv.x + tv.y) + (fv.x + fv.y);
    }
}

extern "C" void kernel_launch(void* const* d_in, const int* in_sizes, int n_in,
                              void* d_out, int out_size, void* d_ws, size_t ws_size,
                              hipStream_t stream) {
    const int*   pos    = (const int*)  d_in[0];   // [16,512,32,2] int32
    const float* fixedt = (const float*)d_in[1];   // [table_len,128] f32
    const float* tx     = (const float*)d_in[2];   // [table_len,128] f32
    const float* ty     = (const float*)d_in[3];   // [table_len,128] f32
    float* out = (float*)d_out;
    unsigned* ws = (unsigned*)d_ws;                // ws[0]=max_x enc, ws[1]=max_y enc

    const int n_table = in_sizes[2];               // table_len * 128
    const int total   = out_size;                  // 16*512*32*128

    // init encoded-max slots to 0 (== -NaN sentinel, below every real float)
    hipMemsetAsync(ws, 0, 2 * sizeof(unsigned), stream);

    // pass 1: maxes (2.1 MB each — trivial)
    {
        int blocks = (n_table + 255) / 256;
        if (blocks > 1024) blocks = 1024;
        table_max_kernel<<<blocks, 256, 0, stream>>>(tx, n_table, ws + 0);
        table_max_kernel<<<blocks, 256, 0, stream>>>(ty, n_table, ws + 1);
    }

    // pass 2: main fused gather (memory-bound, 128 MB out)
    {
        long long want = ((long long)total + 255) / 256;
        int blocks = (want > 2048) ? 2048 : (int)want;
        lookup_kernel<<<blocks, 256, 0, stream>>>(pos, fixedt, tx, ty, ws, out, total);
    }
}

// Round 3
// 52.004 us; speedup vs baseline: 1.9448x; 1.9448x over previous
//
#include <hip/hip_runtime.h>

typedef float f32x4 __attribute__((ext_vector_type(4)));

// ---- order-preserving float<->uint encoding for atomicMax on floats ----
__device__ __forceinline__ unsigned enc_f32(float f) {
    unsigned b = __float_as_uint(f);
    return (b & 0x80000000u) ? ~b : (b | 0x80000000u);
}
__device__ __forceinline__ float dec_f32(unsigned u) {
    unsigned b = (u & 0x80000000u) ? (u & 0x7FFFFFFFu) : ~u;
    return __uint_as_float(b);
}

// ---- pass 1: max of tx -> ws[0], max of ty -> ws[1], one dispatch ----
__global__ void table_max2_kernel(const float* __restrict__ tx,
                                  const float* __restrict__ ty,
                                  int n, unsigned* __restrict__ ws) {
    const int half = gridDim.x >> 1;
    const bool isx = (int)blockIdx.x < half;
    const float* t = isx ? tx : ty;
    unsigned* slot = ws + (isx ? 0 : 1);
    const int b = isx ? blockIdx.x : blockIdx.x - half;
    const int stride = half * blockDim.x;
    float m = -INFINITY;
    for (int i = b * blockDim.x + threadIdx.x; i < n; i += stride)
        m = fmaxf(m, t[i]);
    #pragma unroll
    for (int off = 32; off > 0; off >>= 1)
        m = fmaxf(m, __shfl_down(m, off, 64));
    __shared__ float sm[4];
    int lane = threadIdx.x & 63, wid = threadIdx.x >> 6;
    if (lane == 0) sm[wid] = m;
    __syncthreads();
    if (threadIdx.x == 0) {
        float mm = fmaxf(fmaxf(sm[0], sm[1]), fmaxf(sm[2], sm[3]));
        atomicMax(slot, enc_f32(mm));
    }
}

// ---- pass 2: build pair-summed combined tables (each [rows][64] f32) ----
// cx[p][j] = sx*(tx[p][2j]+tx[p][2j+1]) + (F[p][2j]+F[p][2j+1]); same for cy.
__global__ void build_kernel(const float* __restrict__ fixedt,
                             const float* __restrict__ tx,
                             const float* __restrict__ ty,
                             const unsigned* __restrict__ ws,
                             float* __restrict__ cx, float* __restrict__ cy,
                             int total /* rows*64 */) {
    const float sx = 0.1f / dec_f32(ws[0]);
    const float sy = 0.1f / dec_f32(ws[1]);
    const int stride = gridDim.x * blockDim.x;
    for (int i = blockIdx.x * blockDim.x + threadIdx.x; i < total; i += stride) {
        const int p = i >> 6, j = i & 63;
        const float2 fv = *reinterpret_cast<const float2*>(fixedt + p * 128 + 2 * j);
        const float2 xv = *reinterpret_cast<const float2*>(tx     + p * 128 + 2 * j);
        const float2 yv = *reinterpret_cast<const float2*>(ty     + p * 128 + 2 * j);
        const float f = fv.x + fv.y;
        cx[i] = sx * (xv.x + xv.y) + f;
        cy[i] = sy * (yv.x + yv.y) + f;
    }
}

// ---- pass 3: pure float4 gather from L2-resident combined tables ----
// float4 index i: row = i>>5, q = i&31. q<16 -> cx row pos[2*row], else cy row pos[2*row+1].
__global__ void gather_kernel(const int* __restrict__ pos,
                              const f32x4* __restrict__ cx,
                              const f32x4* __restrict__ cy,
                              f32x4* __restrict__ out, int total4) {
    const int stride = gridDim.x * blockDim.x;
    for (int i = blockIdx.x * blockDim.x + threadIdx.x; i < total4; i += stride) {
        const int q   = i & 31;
        const int row = i >> 5;
        const bool isx = (q < 16);
        int p = pos[2 * row + (isx ? 0 : 1)];   // 16-lane-uniform broadcast load
        if (p < 0) p = 1;
        const f32x4* tab = isx ? cx : cy;
        const int j = isx ? q : q - 16;
        const f32x4 v = tab[p * 16 + j];
        __builtin_nontemporal_store(v, &out[i]);  // don't evict tables from L2
    }
}

// ---- fallback (small ws): direct fused gather, float4 ----
__global__ void direct_kernel(const int* __restrict__ pos,
                              const float* __restrict__ fixedt,
                              const float* __restrict__ tx,
                              const float* __restrict__ ty,
                              const unsigned* __restrict__ ws,
                              f32x4* __restrict__ out, int total4) {
    const float sx = 0.1f / dec_f32(ws[0]);
    const float sy = 0.1f / dec_f32(ws[1]);
    const int stride = gridDim.x * blockDim.x;
    for (int i = blockIdx.x * blockDim.x + threadIdx.x; i < total4; i += stride) {
        const int q   = i & 31;          // float4 slot within 128-float row
        const int row = i >> 5;
        const bool isx = (q < 16);
        int p = pos[2 * row + (isx ? 0 : 1)];
        if (p < 0) p = 1;
        const float s = isx ? sx : sy;
        const float* tab = isx ? tx : ty;
        const int j8 = (isx ? q : q - 16) * 8;   // 8 floats feed one float4 out
        const float4 t0 = *reinterpret_cast<const float4*>(tab + p * 128 + j8);
        const float4 t1 = *reinterpret_cast<const float4*>(tab + p * 128 + j8 + 4);
        const float4 f0 = *reinterpret_cast<const float4*>(fixedt + p * 128 + j8);
        const float4 f1 = *reinterpret_cast<const float4*>(fixedt + p * 128 + j8 + 4);
        f32x4 v;
        v.x = s * (t0.x + t0.y) + (f0.x + f0.y);
        v.y = s * (t0.z + t0.w) + (f0.z + f0.w);
        v.z = s * (t1.x + t1.y) + (f1.x + f1.y);
        v.w = s * (t1.z + t1.w) + (f1.z + f1.w);
        __builtin_nontemporal_store(v, &out[i]);
    }
}

extern "C" void kernel_launch(void* const* d_in, const int* in_sizes, int n_in,
                              void* d_out, int out_size, void* d_ws, size_t ws_size,
                              hipStream_t stream) {
    const int*   pos    = (const int*)  d_in[0];   // [16,512,32,2]
    const float* fixedt = (const float*)d_in[1];   // [table_len,128]
    const float* tx     = (const float*)d_in[2];
    const float* ty     = (const float*)d_in[3];
    float* out = (float*)d_out;
    unsigned* ws = (unsigned*)d_ws;

    const int n_table  = in_sizes[2];              // table_len * 128
    const int rows     = n_table >> 7;             // table_len
    const int total    = out_size;                 // 33.5M
    const int total4   = total >> 2;

    // ws layout: [0..1] encoded maxes; combined tables at 256 B offset
    const size_t c_off_f = 64;                              // floats
    const size_t need = 256 + (size_t)rows * 64 * 4 * 2;    // bytes

    (void)hipMemsetAsync(ws, 0, 2 * sizeof(unsigned), stream);
    table_max2_kernel<<<1024, 256, 0, stream>>>(tx, ty, n_table, ws);

    if (ws_size >= need) {
        float* cx = (float*)ws + c_off_f;
        float* cy = cx + (size_t)rows * 64;
        int btot = rows * 64;
        build_kernel<<<(btot + 255) / 256, 256, 0, stream>>>(fixedt, tx, ty, ws, cx, cy, btot);
        gather_kernel<<<2048, 256, 0, stream>>>(pos, (const f32x4*)cx, (const f32x4*)cy,
                                                (f32x4*)out, total4);
    } else {
        direct_kernel<<<2048, 256, 0, stream>>>(pos, fixedt, tx, ty, ws,
                                                (f32x4*)out, total4);
    }
}